// Round 1
// baseline (316.330 us; speedup 1.0000x reference)
//
#include <hip/hip_runtime.h>
#include <hip/hip_bf16.h>

// Shapes: bottom (8,256,128,128) f32; w1 (256,1,3,3); a1,w2,b2 (256,)
// Out: res (8,256,64,64) then pexp (8,256,64,64), both f32, concatenated.
// K=3, S=2, P=1 -> Ho=Wo=64. Plane = 128*128 = 16384 elems. B*C = 2048 planes.

#define HW 16384      // 128*128
#define PLANE_OUT 4096 // 64*64
#define N_OUT 8388608  // 8*256*64*64

// Kernel 1: per-(b,c) max(|x|) + 1 -> m[bc]
__global__ __launch_bounds__(256) void bc_max_kernel(
    const float* __restrict__ bottom, float* __restrict__ m_out) {
    int bc = blockIdx.x;
    const float4* p = reinterpret_cast<const float4*>(bottom + (size_t)bc * HW);
    float mx = 0.f;
    #pragma unroll 4
    for (int i = threadIdx.x; i < HW / 4; i += 256) {
        float4 v = p[i];
        mx = fmaxf(mx, fmaxf(fmaxf(fabsf(v.x), fabsf(v.y)),
                             fmaxf(fabsf(v.z), fabsf(v.w))));
    }
    // wave(64) reduce
    #pragma unroll
    for (int off = 32; off > 0; off >>= 1)
        mx = fmaxf(mx, __shfl_down(mx, off, 64));
    __shared__ float smax[4];
    int wid = threadIdx.x >> 6;
    if ((threadIdx.x & 63) == 0) smax[wid] = mx;
    __syncthreads();
    if (threadIdx.x == 0) {
        mx = fmaxf(fmaxf(smax[0], smax[1]), fmaxf(smax[2], smax[3]));
        m_out[bc] = mx + 1.0f;
    }
}

// Kernel 2: fused exponent-branch + p-pooling. One thread per output elem.
__global__ __launch_bounds__(256) void ppool_kernel(
    const float* __restrict__ bottom,
    const float* __restrict__ w1,   // (256,3,3)
    const float* __restrict__ a1,   // (256,)
    const float* __restrict__ w2,   // (256,)
    const float* __restrict__ b2,   // (256,)
    const float* __restrict__ m_in, // (2048,)
    float* __restrict__ out) {
    int idx = blockIdx.x * 256 + threadIdx.x;   // 0 .. N_OUT-1
    int wo = idx & 63;
    int ho = (idx >> 6) & 63;
    int bc = idx >> 12;           // b*256 + c
    int c  = bc & 255;

    const float* plane = bottom + (size_t)bc * HW;
    float inv_m = 1.0f / m_in[bc];

    float wk[9];
    #pragma unroll
    for (int t = 0; t < 9; ++t) wk[t] = w1[c * 9 + t];

    int h0 = ho * 2 - 1;
    int w0 = wo * 2 - 1;

    float px[9];
    float v = 0.f;
    #pragma unroll
    for (int i = 0; i < 3; ++i) {
        int hi = h0 + i;
        bool hok = (unsigned)hi < 128u;
        const float* row = plane + hi * 128;
        #pragma unroll
        for (int j = 0; j < 3; ++j) {
            int wi = w0 + j;
            float x = (hok && (unsigned)wi < 128u) ? row[wi] : 0.f;
            v += wk[i * 3 + j] * x;
            px[i * 3 + j] = fmaxf(x, 0.f);
        }
    }
    v *= inv_m;                                   // conv of (bottom/m)
    float slope = a1[c];
    v = v > 0.f ? v : slope * v;                  // PReLU
    float p = v * w2[c] + b2[c];                  // 1x1 dw conv + bias
    p = fminf(fmaxf(p, 1.0f), 110.0f);            // hardtanh clip

    float s = 0.f;
    #pragma unroll
    for (int t = 0; t < 9; ++t) {
        float x = px[t];
        s += (x > 0.f) ? __powf(x, p) : 0.f;
    }
    float mp = s * (1.0f / 9.0f) + 1e-12f;
    float res = __powf(mp, 1.0f / p);

    out[idx] = res;
    out[N_OUT + idx] = p;
}

extern "C" void kernel_launch(void* const* d_in, const int* in_sizes, int n_in,
                              void* d_out, int out_size, void* d_ws, size_t ws_size,
                              hipStream_t stream) {
    const float* bottom = (const float*)d_in[0];
    const float* w1     = (const float*)d_in[1];
    const float* a1     = (const float*)d_in[2];
    const float* w2     = (const float*)d_in[3];
    const float* b2     = (const float*)d_in[4];
    float* out = (float*)d_out;
    float* m   = (float*)d_ws;   // 2048 floats

    bc_max_kernel<<<2048, 256, 0, stream>>>(bottom, m);
    ppool_kernel<<<N_OUT / 256, 256, 0, stream>>>(bottom, w1, a1, w2, b2, m, out);
}

// Round 2
// 68.028 us; speedup vs baseline: 4.6500x; 4.6500x over previous
//
#include <hip/hip_runtime.h>
#include <hip/hip_bf16.h>

// Shapes: bottom (8,256,128,128) f32; w1 (256,1,3,3); a1,w2,b2 (256,)
// Out: res (8,256,64,64) then pexp (8,256,64,64), both f32, concatenated.
// K=3, S=2, P=1 -> Ho=Wo=64. Plane = 128*128 = 16384 elems. B*C = 2048 planes.

#define HW 16384       // 128*128
#define N_OUT 8388608  // 8*256*64*64

// Fast hardware transcendentals (1-ulp class): v_log_f32 = log2, v_exp_f32 = exp2.
__device__ __forceinline__ float hw_log2(float x) { return __builtin_amdgcn_logf(x); }
__device__ __forceinline__ float hw_exp2(float x) { return __builtin_amdgcn_exp2f(x); }
__device__ __forceinline__ float hw_rcp(float x)  { return __builtin_amdgcn_rcpf(x); }

// Kernel 1: per-(b,c) max(|x|) + 1 -> m[bc]
__global__ __launch_bounds__(256) void bc_max_kernel(
    const float* __restrict__ bottom, float* __restrict__ m_out) {
    int bc = blockIdx.x;
    const float4* p = reinterpret_cast<const float4*>(bottom + (size_t)bc * HW);
    float mx = 0.f;
    #pragma unroll 4
    for (int i = threadIdx.x; i < HW / 4; i += 256) {
        float4 v = p[i];
        mx = fmaxf(mx, fmaxf(fmaxf(fabsf(v.x), fabsf(v.y)),
                             fmaxf(fabsf(v.z), fabsf(v.w))));
    }
    #pragma unroll
    for (int off = 32; off > 0; off >>= 1)
        mx = fmaxf(mx, __shfl_down(mx, off, 64));
    __shared__ float smax[4];
    int wid = threadIdx.x >> 6;
    if ((threadIdx.x & 63) == 0) smax[wid] = mx;
    __syncthreads();
    if (threadIdx.x == 0) {
        mx = fmaxf(fmaxf(smax[0], smax[1]), fmaxf(smax[2], smax[3]));
        m_out[bc] = mx + 1.0f;
    }
}

// Kernel 2: fused exponent-branch + p-pooling. One thread per output elem.
__global__ __launch_bounds__(256) void ppool_kernel(
    const float* __restrict__ bottom,
    const float* __restrict__ w1,   // (256,3,3)
    const float* __restrict__ a1,   // (256,)
    const float* __restrict__ w2,   // (256,)
    const float* __restrict__ b2,   // (256,)
    const float* __restrict__ m_in, // (2048,)
    float* __restrict__ out) {
    int idx = blockIdx.x * 256 + threadIdx.x;   // 0 .. N_OUT-1
    int wo = idx & 63;
    int ho = (idx >> 6) & 63;
    int bc = idx >> 12;           // b*256 + c
    int c  = bc & 255;

    const float* plane = bottom + (size_t)bc * HW;
    float inv_m = hw_rcp(m_in[bc]);             // 1/m, 1-ulp

    float wk[9];
    #pragma unroll
    for (int t = 0; t < 9; ++t) wk[t] = w1[c * 9 + t];

    int h0 = ho * 2 - 1;
    int w0 = wo * 2 - 1;

    float px[9];
    float v = 0.f;
    #pragma unroll
    for (int i = 0; i < 3; ++i) {
        int hi = h0 + i;
        bool hok = (unsigned)hi < 128u;
        const float* row = plane + hi * 128;
        #pragma unroll
        for (int j = 0; j < 3; ++j) {
            int wi = w0 + j;
            float x = (hok && (unsigned)wi < 128u) ? row[wi] : 0.f;
            v += wk[i * 3 + j] * x;
            px[i * 3 + j] = fmaxf(x, 0.f);
        }
    }
    v *= inv_m;                                   // conv of (bottom/m)
    float slope = a1[c];
    v = v > 0.f ? v : slope * v;                  // PReLU
    float p = v * w2[c] + b2[c];                  // 1x1 dw conv + bias
    p = fminf(fmaxf(p, 1.0f), 110.0f);            // hardtanh clip

    // power-mean: x^p = exp2(p * log2(x)) via hardware trans ops
    float s = 0.f;
    #pragma unroll
    for (int t = 0; t < 9; ++t) {
        float x = px[t];
        float e = hw_exp2(p * hw_log2(x));        // x=0 -> exp2(-inf)=0
        s += (x > 0.f) ? e : 0.f;
    }
    float mp = s * (1.0f / 9.0f) + 1e-12f;
    float res = hw_exp2(hw_log2(mp) * hw_rcp(p));

    out[idx] = res;
    out[N_OUT + idx] = p;
}

extern "C" void kernel_launch(void* const* d_in, const int* in_sizes, int n_in,
                              void* d_out, int out_size, void* d_ws, size_t ws_size,
                              hipStream_t stream) {
    const float* bottom = (const float*)d_in[0];
    const float* w1     = (const float*)d_in[1];
    const float* a1     = (const float*)d_in[2];
    const float* w2     = (const float*)d_in[3];
    const float* b2     = (const float*)d_in[4];
    float* out = (float*)d_out;
    float* m   = (float*)d_ws;   // 2048 floats

    bc_max_kernel<<<2048, 256, 0, stream>>>(bottom, m);
    ppool_kernel<<<N_OUT / 256, 256, 0, stream>>>(bottom, w1, a1, w2, b2, m, out);
}

// Round 3
// 42.777 us; speedup vs baseline: 7.3948x; 1.5903x over previous
//
#include <hip/hip_runtime.h>
#include <hip/hip_bf16.h>

// bottom (8,256,128,128) f32; w1 (256,1,3,3); a1,w2,b2 (256,)
// out: res (8,256,64,64) ++ pexp (8,256,64,64), f32.
// K=3 S=2 P=1 -> Ho=Wo=64. One block per (b,c) plane; 2048 blocks.

#define HW 16384       // 128*128
#define N_OUT 8388608  // 8*256*64*64

__device__ __forceinline__ float hw_log2(float x) { return __builtin_amdgcn_logf(x); }
__device__ __forceinline__ float hw_exp2(float x) { return __builtin_amdgcn_exp2f(x); }
__device__ __forceinline__ float hw_rcp(float x)  { return __builtin_amdgcn_rcpf(x); }

__global__ __launch_bounds__(1024, 8) void fused_ppool_kernel(
    const float* __restrict__ bottom,
    const float* __restrict__ w1,   // (256,3,3)
    const float* __restrict__ a1,
    const float* __restrict__ w2,
    const float* __restrict__ b2,
    float* __restrict__ out) {
    __shared__ float plane[HW];     // 64 KiB
    __shared__ float smax[16];

    const int bc   = blockIdx.x;    // b*256 + c
    const int c    = bc & 255;
    const int t    = threadIdx.x;
    const int wid  = t >> 6;
    const int lane = t & 63;

    // ---- Phase 1: stream plane into LDS, compute max(|x|) ----
    const float4* src = reinterpret_cast<const float4*>(bottom + (size_t)bc * HW);
    float4* pl4 = reinterpret_cast<float4*>(plane);
    float mx = 0.f;
    #pragma unroll
    for (int k = 0; k < 4; ++k) {
        float4 v = src[t + k * 1024];
        pl4[t + k * 1024] = v;
        mx = fmaxf(mx, fmaxf(fmaxf(fabsf(v.x), fabsf(v.y)),
                             fmaxf(fabsf(v.z), fabsf(v.w))));
    }
    #pragma unroll
    for (int off = 32; off; off >>= 1)
        mx = fmaxf(mx, __shfl_down(mx, off, 64));
    if (lane == 0) smax[wid] = mx;
    __syncthreads();

    float m = 0.f;
    #pragma unroll
    for (int k = 0; k < 16; ++k) m = fmaxf(m, smax[k]);
    const float inv_m = hw_rcp(m + 1.0f);

    // block-uniform channel params -> scalar loads
    float wk[9];
    #pragma unroll
    for (int k = 0; k < 9; ++k) wk[k] = w1[c * 9 + k];
    const float slope = a1[c];
    const float ww2   = w2[c];
    const float bb2   = b2[c];

    float* outres = out + (size_t)bc * 4096;
    float* outp   = out + N_OUT + (size_t)bc * 4096;

    // ---- Phase 2: each wave handles output rows wid, wid+16, wid+32, wid+48 ----
    #pragma unroll
    for (int rr = 0; rr < 4; ++rr) {
        const int ho = wid + rr * 16;   // output row; lane = wo
        float xw[3][3];                 // [kernel row][col: 2wo-1, 2wo, 2wo+1]
        #pragma unroll
        for (int r = 0; r < 3; ++r) {
            const int hi = 2 * ho - 1 + r;      // wave-uniform
            float x0 = 0.f, x1 = 0.f, xm = 0.f;
            if ((unsigned)hi < 128u) {
                float2 v = *reinterpret_cast<const float2*>(&plane[hi * 128 + lane * 2]);
                x0 = v.x; x1 = v.y;
                xm = __shfl_up(x1, 1, 64);      // col 2wo-1 from left neighbor
                if (lane == 0) xm = 0.f;        // zero pad at col -1
            }
            xw[r][0] = xm; xw[r][1] = x0; xw[r][2] = x1;
        }

        // depthwise 3x3 conv of (x * inv_m)
        float v = 0.f;
        #pragma unroll
        for (int r = 0; r < 3; ++r)
            #pragma unroll
            for (int j = 0; j < 3; ++j)
                v += wk[r * 3 + j] * xw[r][j];
        v *= inv_m;
        v = v > 0.f ? v : slope * v;            // PReLU
        float p = v * ww2 + bb2;                // 1x1 dw conv + bias
        p = fminf(fmaxf(p, 1.0f), 110.0f);      // hardtanh

        // power-mean over relu(window)^p
        float s = 0.f;
        #pragma unroll
        for (int r = 0; r < 3; ++r) {
            #pragma unroll
            for (int j = 0; j < 3; ++j) {
                float x = fmaxf(xw[r][j], 0.f);
                float e = hw_exp2(p * hw_log2(x));   // x=0 -> exp2(-inf)=0
                s += (x > 0.f) ? e : 0.f;
            }
        }
        float mp  = s * (1.0f / 9.0f) + 1e-12f;
        float res = hw_exp2(hw_log2(mp) * hw_rcp(p));

        outres[ho * 64 + lane] = res;
        outp  [ho * 64 + lane] = p;
    }
}

extern "C" void kernel_launch(void* const* d_in, const int* in_sizes, int n_in,
                              void* d_out, int out_size, void* d_ws, size_t ws_size,
                              hipStream_t stream) {
    const float* bottom = (const float*)d_in[0];
    const float* w1     = (const float*)d_in[1];
    const float* a1     = (const float*)d_in[2];
    const float* w2     = (const float*)d_in[3];
    const float* b2     = (const float*)d_in[4];
    float* out = (float*)d_out;

    fused_ppool_kernel<<<2048, 1024, 0, stream>>>(bottom, w1, a1, w2, b2, out);
}